// Round 12
// baseline (895.217 us; speedup 1.0000x reference)
//
#include <hip/hip_runtime.h>

#define HD    256
#define HD2   128
#define SDIM  512
#define GNUM  64
#define NN    100000
#define NE    200000
#define NENT  20000
#define NREL  500
#define BNUM  32
#define SEQL  10

typedef __attribute__((ext_vector_type(4))) float f32x4;
typedef __attribute__((ext_vector_type(8))) short bf16x8;

__device__ __forceinline__ short to_bf(float f) {
    unsigned u = __float_as_uint(f);
    u += 0x7fff + ((u >> 16) & 1);
    return (short)(u >> 16);
}

// ---------------- CSR build ----------------

__global__ void k_cnt(const int* __restrict__ edst, int* __restrict__ cnt) {
    int e = blockIdx.x * 256 + threadIdx.x;
    if (e < NE) atomicAdd(&cnt[edst[e]], 1);
}

__global__ void k_scan_blk(const int* __restrict__ cnt, int* __restrict__ row_off,
                           int* __restrict__ bsum) {
    __shared__ int s[256];
    int i = blockIdx.x * 256 + threadIdx.x;
    int v = cnt[i];
    s[threadIdx.x] = v;
    __syncthreads();
    for (int d = 1; d < 256; d <<= 1) {
        int t = (threadIdx.x >= d) ? s[threadIdx.x - d] : 0;
        __syncthreads();
        s[threadIdx.x] += t;
        __syncthreads();
    }
    row_off[i] = s[threadIdx.x] - v;  // exclusive
    if (threadIdx.x == 255) bsum[blockIdx.x] = s[255];
}

__global__ void k_scan_top(int* __restrict__ bsum) {  // 391 partials
    __shared__ int s[512];
    int v = (threadIdx.x < 391) ? bsum[threadIdx.x] : 0;
    s[threadIdx.x] = v;
    __syncthreads();
    for (int d = 1; d < 512; d <<= 1) {
        int t = (threadIdx.x >= d) ? s[threadIdx.x - d] : 0;
        __syncthreads();
        s[threadIdx.x] += t;
        __syncthreads();
    }
    if (threadIdx.x < 391) bsum[threadIdx.x] = s[threadIdx.x] - v;  // exclusive
}

__global__ void k_scan_add(int* __restrict__ row_off, const int* __restrict__ bsum,
                           int* __restrict__ cur) {
    int i = blockIdx.x * 256 + threadIdx.x;
    int v = row_off[i] + bsum[blockIdx.x];
    row_off[i] = v;
    cur[i] = v;
}

// CSR-ordered edge arrays
__global__ void k_fill(const int* __restrict__ edst, const int* __restrict__ esrc,
                       const int* __restrict__ etype, const int* __restrict__ node_ids,
                       int* __restrict__ cur, int* __restrict__ eidx,
                       int* __restrict__ esrcC, int* __restrict__ etC,
                       int* __restrict__ nidC) {
    int e = blockIdx.x * 256 + threadIdx.x;
    if (e < NE) {
        int pos = atomicAdd(&cur[edst[e]], 1);
        int s = esrc[e];
        eidx[pos] = e;
        esrcC[pos] = s;
        etC[pos] = etype[e];
        nidC[pos] = node_ids[s];
    }
}

// ---------------- small per-relation kernels ----------------

__global__ void k_rel_feat(const float* __restrict__ rel_emb, const float* __restrict__ rel_mem,
                           const float* __restrict__ W, const float* __restrict__ b,
                           float* __restrict__ rel_feat) {
    __shared__ float s[768];
    int r = blockIdx.x, j = threadIdx.x;
    for (int k = j; k < 768; k += 256)
        s[k] = (k < 512) ? rel_emb[r * 512 + k] : rel_mem[r * 256 + (k - 512)];
    __syncthreads();
    float acc = b[j];
    for (int k = 0; k < 768; ++k) acc += s[k] * W[k * 256 + j];
    rel_feat[r * 256 + j] = acc;
}

__global__ void k_rel_l1(const float* __restrict__ rel_feat, const float* __restrict__ Wn1,
                         const float* __restrict__ Wr1, float* __restrict__ ecomb,
                         float* __restrict__ er1) {
    __shared__ float s[256];
    int r = blockIdx.x, j = threadIdx.x;
    s[j] = rel_feat[r * 256 + j];
    __syncthreads();
    if (j < 128) {
        float acc = 0.f;
        for (int k = 0; k < 256; ++k) acc += s[k] * Wn1[k * 128 + j];
        ecomb[r * 384 + j] = acc;
    } else {
        int jj = j - 128;
        float acc = 0.f;
        for (int k = 0; k < 256; ++k) acc += s[k] * Wr1[k * 128 + jj];
        er1[r * 128 + jj] = fmaxf(acc, 0.f);
    }
}

__global__ void k_rel_l2(const float* __restrict__ er1, const float* __restrict__ Wr2,
                         const float* __restrict__ Wn2, float* __restrict__ er2,
                         float* __restrict__ ecomb) {
    __shared__ float s[128];
    int r = blockIdx.x, j = threadIdx.x;
    if (j < 128) s[j] = er1[r * 128 + j];
    __syncthreads();
    float a = 0.f, c = 0.f;
    for (int k = 0; k < 128; ++k) {
        float v = s[k];
        a += v * Wr2[k * 256 + j];
        c += v * Wn2[k * 256 + j];
    }
    er2[r * 256 + j] = fmaxf(a, 0.f);
    ecomb[r * 384 + 128 + j] = c;
}

// ---------------- combined node weights: cw = w_node_W @ [Wn1|Wl1] ----------------

__global__ void k_cw(const float* __restrict__ wnW, const float* __restrict__ Wn1,
                     const float* __restrict__ Wl1, float* __restrict__ cw) {
    __shared__ float s[256];
    int k = blockIdx.x, j = threadIdx.x;
    s[j] = wnW[k * 256 + j];
    __syncthreads();
    float acc = 0.f;
    if (j < 128) {
        for (int m = 0; m < 256; ++m) acc += s[m] * Wn1[m * 128 + j];
    } else {
        int jj = j - 128;
        for (int m = 0; m < 256; ++m) acc += s[m] * Wl1[m * 128 + jj];
    }
    cw[k * 256 + j] = acc;
}

__global__ void k_cb(const float* __restrict__ wnb, const float* __restrict__ Wn1,
                     const float* __restrict__ Wl1, float* __restrict__ bc) {
    int j = threadIdx.x;
    float acc = 0.f;
    if (j < 128) {
        for (int m = 0; m < 256; ++m) acc += wnb[m] * Wn1[m * 128 + j];
    } else {
        int jj = j - 128;
        for (int m = 0; m < 256; ++m) acc += wnb[m] * Wl1[m * 128 + jj];
    }
    bc[j] = acc;
}

// ---------------- generic weight packer: f32 [KxN] -> bf16 B-frags ----------------
__global__ void k_pack(const float* __restrict__ src, bf16x8* __restrict__ dst,
                       int K, int N) {
    int KF = K >> 5;
    int fid = blockIdx.x;
    int n = fid / KF, kk = fid - n * KF;
    int lane = threadIdx.x;
    int col = n * 16 + (lane & 15);
    int kb = kk * 32 + (lane >> 4) * 8;
    bf16x8 v;
#pragma unroll
    for (int j = 0; j < 8; ++j) v[j] = to_bf(src[(size_t)(kb + j) * N + col]);
    dst[(size_t)fid * 64 + lane] = v;
}

// ---------------- entity GEMM: [ee|em] @ cw -> ha1, hb1 ----------------

__global__ void __launch_bounds__(256) k_ent(const float* __restrict__ ee,
                                             const float* __restrict__ em,
                                             const bf16x8* __restrict__ cwf,
                                             const float* __restrict__ bc,
                                             float* __restrict__ ha1,
                                             float* __restrict__ hb1) {
    __shared__ bf16x8 sA[2048];  // 32KB
    int tid = threadIdx.x;
    int e0 = blockIdx.x * 64;
    int wave = tid >> 6, lane = tid & 63;
    int gs = (tid >> 4) & 3, rs = tid & 15;
    int rowS = ((tid >> 6) & 3) * 16 + rs;
    int ent = e0 + rowS;
    if (ent >= NENT) ent = NENT - 1;
    f32x4 acc[4][4];
#pragma unroll
    for (int mf = 0; mf < 4; ++mf)
#pragma unroll
        for (int nf = 0; nf < 4; ++nf) acc[mf][nf] = (f32x4)0.f;

    for (int ch = 0; ch < 3; ++ch) {
        if (ch) __syncthreads();
#pragma unroll
        for (int it = 0; it < 8; ++it) {
            int gc = ch * 256 + it * 32 + gs * 8;
            const float4* p = (gc < 512)
                ? (const float4*)(ee + (size_t)ent * 512 + gc)
                : (const float4*)(em + (size_t)ent * 256 + (gc - 512));
            float4 x = p[0], y = p[1];
            bf16x8 v;
            v[0] = to_bf(x.x); v[1] = to_bf(x.y); v[2] = to_bf(x.z); v[3] = to_bf(x.w);
            v[4] = to_bf(y.x); v[5] = to_bf(y.y); v[6] = to_bf(y.z); v[7] = to_bf(y.w);
            sA[it * 256 + tid] = v;
        }
        __syncthreads();
#pragma unroll
        for (int kkl = 0; kkl < 8; ++kkl) {
            bf16x8 a[4], b[4];
#pragma unroll
            for (int mf = 0; mf < 4; ++mf) a[mf] = sA[kkl * 256 + mf * 64 + lane];
#pragma unroll
            for (int nf = 0; nf < 4; ++nf)
                b[nf] = cwf[(size_t)((wave * 4 + nf) * 24 + ch * 8 + kkl) * 64 + lane];
#pragma unroll
            for (int mf = 0; mf < 4; ++mf)
#pragma unroll
                for (int nf = 0; nf < 4; ++nf)
                    acc[mf][nf] = __builtin_amdgcn_mfma_f32_16x16x32_bf16(a[mf], b[nf],
                                                                          acc[mf][nf], 0, 0, 0);
        }
    }
    int gq = lane >> 4, cl = lane & 15;
#pragma unroll
    for (int mf = 0; mf < 4; ++mf)
#pragma unroll
        for (int nf = 0; nf < 4; ++nf) {
            int c = wave * 64 + nf * 16 + cl;
            float bb = bc[c];
#pragma unroll
            for (int q = 0; q < 4; ++q) {
                int m = e0 + mf * 16 + gq * 4 + q;
                if (m < NENT) {
                    float val = acc[mf][nf][q] + bb;
                    if (c < 128) ha1[(size_t)m * 128 + c] = val;
                    else hb1[(size_t)m * 128 + (c - 128)] = val;
                }
            }
        }
}

// ---------------- k_tsum: per-node text-sum + table-fold sums (1 wave per node) ----------------
// tsumb[n] = bf16(sum_e text[e]) ; fold[n][0:128] = sum ha1[nid] - sum ecomb[et][0:128],
// fold[n][128:384] = -sum ecomb[et][128:384].

__global__ void __launch_bounds__(256) k_tsum(const float* __restrict__ text,
                                              const int* __restrict__ row_off,
                                              const int* __restrict__ eidx,
                                              const int* __restrict__ etC,
                                              const int* __restrict__ nidC,
                                              const float* __restrict__ ha1,
                                              const float* __restrict__ ecomb,
                                              unsigned short* __restrict__ tsumb,
                                              float* __restrict__ fold) {
    int n = blockIdx.x * 4 + (threadIdx.x >> 6);
    int lane = threadIdx.x & 63;
    if (n >= NN) return;
    int beg = row_off[n], end = row_off[n + 1];
    int c = lane * 2;
    f32x4 t0 = (f32x4)0.f, t1 = (f32x4)0.f;
    float f0 = 0.f, f1 = 0.f, f2 = 0.f, f3 = 0.f, f4 = 0.f, f5 = 0.f;
    float h0 = 0.f, h1v = 0.f;
    for (int i = beg; i < end; ++i) {
        const float* tr = text + (size_t)eidx[i] * 512 + lane * 8;
        t0 += *(const f32x4*)tr;
        t1 += *(const f32x4*)(tr + 4);
        int et = etC[i], nid = nidC[i];
        const float2 e0 = *(const float2*)(ecomb + (size_t)et * 384 + c);
        const float2 e1 = *(const float2*)(ecomb + (size_t)et * 384 + 128 + c);
        const float2 e2 = *(const float2*)(ecomb + (size_t)et * 384 + 256 + c);
        const float2 hv = *(const float2*)(ha1 + (size_t)nid * 128 + c);
        f0 -= e0.x; f1 -= e0.y;
        f2 -= e1.x; f3 -= e1.y;
        f4 -= e2.x; f5 -= e2.y;
        h0 += hv.x; h1v += hv.y;
    }
    bf16x8 tb;
    tb[0] = to_bf(t0[0]); tb[1] = to_bf(t0[1]); tb[2] = to_bf(t0[2]); tb[3] = to_bf(t0[3]);
    tb[4] = to_bf(t1[0]); tb[5] = to_bf(t1[1]); tb[6] = to_bf(t1[2]); tb[7] = to_bf(t1[3]);
    *(bf16x8*)(tsumb + (size_t)n * 512 + lane * 8) = tb;
    float2 w0; w0.x = f0 + h0; w0.y = f1 + h1v;
    float2 w1; w1.x = f2; w1.y = f3;
    float2 w2; w2.x = f4; w2.y = f5;
    *(float2*)(fold + (size_t)n * 384 + c) = w0;
    *(float2*)(fold + (size_t)n * 384 + 128 + c) = w1;
    *(float2*)(fold + (size_t)n * 384 + 256 + c) = w2;
}

// ---------------- k_node: dense node GEMM tsumb @ [Wt1|Wt2] + fold -> h1, agg2 ----------------

__global__ void __launch_bounds__(256, 2) k_node(const unsigned short* __restrict__ tsumb,
                                                 const float* __restrict__ fold,
                                                 const int* __restrict__ node_ids,
                                                 const int* __restrict__ cnt,
                                                 const bf16x8* __restrict__ wtf,
                                                 const float* __restrict__ hb1,
                                                 const float* __restrict__ b1,
                                                 float* __restrict__ h1,
                                                 float* __restrict__ agg2) {
    __shared__ bf16x8 sA[4096];  // 64KB: 64 rows x 512 bf16 in frag order
    __shared__ int s_nid[64];
    int tid = threadIdx.x;
    int n0 = blockIdx.x * 64;
    if (tid < 64) {
        int m = n0 + tid;
        if (m >= NN) m = NN - 1;
        s_nid[tid] = node_ids[m];
    }
    int R = ((tid >> 6) << 4) + (tid & 15);
    int g = (tid >> 4) & 3;
    int rowm = n0 + R;
    if (rowm >= NN) rowm = NN - 1;
    const unsigned short* trow = tsumb + (size_t)rowm * 512 + g * 8;
    // bulk burst: 16 x 16B loads (bf16 already — pure copy to LDS frag slots)
    bf16x8 rv[16];
#pragma unroll
    for (int kk = 0; kk < 16; ++kk) rv[kk] = *(const bf16x8*)(trow + kk * 32);
#pragma unroll
    for (int kk = 0; kk < 16; ++kk) sA[kk * 256 + tid] = rv[kk];
    __syncthreads();

    int wave = tid >> 6, lane = tid & 63;
    f32x4 acc[4][6];
#pragma unroll
    for (int mf = 0; mf < 4; ++mf)
#pragma unroll
        for (int nf = 0; nf < 6; ++nf) acc[mf][nf] = (f32x4)0.f;

#pragma unroll
    for (int kk = 0; kk < 16; ++kk) {
        bf16x8 a[4], b[6];
#pragma unroll
        for (int mf = 0; mf < 4; ++mf) a[mf] = sA[kk * 256 + mf * 64 + lane];
#pragma unroll
        for (int nf = 0; nf < 6; ++nf)
            b[nf] = wtf[(size_t)((wave * 6 + nf) * 16 + kk) * 64 + lane];
#pragma unroll
        for (int mf = 0; mf < 4; ++mf)
#pragma unroll
            for (int nf = 0; nf < 6; ++nf)
                acc[mf][nf] = __builtin_amdgcn_mfma_f32_16x16x32_bf16(a[mf], b[nf],
                                                                      acc[mf][nf], 0, 0, 0);
    }

    int gq = lane >> 4, cl = lane & 15;
    // -------- loads-only epilogue phase --------
    float dinv[4][4];
#pragma unroll
    for (int mf = 0; mf < 4; ++mf)
#pragma unroll
        for (int q = 0; q < 4; ++q) {
            int m = n0 + mf * 16 + gq * 4 + q;
            if (m >= NN) m = NN - 1;
            dinv[mf][q] = 1.f / fmaxf((float)cnt[m], 1.f);
        }
#pragma unroll
    for (int mf = 0; mf < 4; ++mf)
#pragma unroll
        for (int nf = 0; nf < 6; ++nf) {
            int c = wave * 96 + nf * 16 + cl;
            float bb = (c < 128) ? b1[c] : 0.f;
#pragma unroll
            for (int q = 0; q < 4; ++q) {
                int row = mf * 16 + gq * 4 + q;
                int m = n0 + row;
                if (m >= NN) m = NN - 1;
                float v = acc[mf][nf][q] + fold[(size_t)m * 384 + c];
                if (c < 128) {
                    int nid = s_nid[row];
                    v = fmaxf(v * dinv[mf][q] + hb1[(size_t)nid * 128 + c] + bb, 0.f);
                }
                acc[mf][nf][q] = v;
            }
        }
    __builtin_amdgcn_sched_barrier(0);
    // -------- stores-only phase --------
#pragma unroll
    for (int mf = 0; mf < 4; ++mf)
#pragma unroll
        for (int nf = 0; nf < 6; ++nf) {
            int c = wave * 96 + nf * 16 + cl;
#pragma unroll
            for (int q = 0; q < 4; ++q) {
                int m = n0 + mf * 16 + gq * 4 + q;
                if (m < NN) {
                    if (c < 128) h1[(size_t)m * 128 + c] = acc[mf][nf][q];
                    else agg2[(size_t)m * 256 + (c - 128)] = acc[mf][nf][q];
                }
            }
        }
}

// ---------------- k_s1: s1[n] = sum over incoming edges of h1[src] ----------------

__global__ void __launch_bounds__(256) k_s1(const float* __restrict__ h1,
                                            const int* __restrict__ row_off,
                                            const int* __restrict__ esrcC,
                                            float* __restrict__ s1) {
    int n = blockIdx.x * 4 + (threadIdx.x >> 6);
    int lane = threadIdx.x & 63;
    if (n >= NN) return;
    int beg = row_off[n], end = row_off[n + 1];
    float2 acc; acc.x = 0.f; acc.y = 0.f;
    for (int i = beg; i < end; ++i) {
        int src = esrcC[i];
        float2 v = ((const float2*)(h1 + (size_t)src * 128))[lane];
        acc.x += v.x; acc.y += v.y;
    }
    ((float2*)(s1 + (size_t)n * 128))[lane] = acc;
}

// ---------------- h2: pure dual GEMM + split epilogue ----------------

__global__ void __launch_bounds__(256) k_h2(const float* __restrict__ s1,
                                            const float* __restrict__ h1,
                                            const float* __restrict__ agg2,
                                            const int* __restrict__ cnt,
                                            const bf16x8* __restrict__ wn2f,
                                            const bf16x8* __restrict__ wl2f,
                                            const float* __restrict__ b2,
                                            float* __restrict__ h2) {
    __shared__ bf16x8 sS[1024], sH[1024];  // 16KB each
    int tid = threadIdx.x, n0 = blockIdx.x * 64;
    int wave = tid >> 6, lane = tid & 63;
    {
        int gsv = (tid >> 4) & 3, rsv = tid & 15;
        int row = ((tid >> 6) & 3) * 16 + rsv;
        int m = n0 + row;
        if (m >= NN) m = NN - 1;
#pragma unroll
        for (int kk = 0; kk < 4; ++kk) {
            int cb = kk * 32 + gsv * 8;
            const float4* ps = (const float4*)(s1 + (size_t)m * 128 + cb);
            const float4* ph = (const float4*)(h1 + (size_t)m * 128 + cb);
            float4 sx = ps[0], sy = ps[1], hx = ph[0], hy = ph[1];
            bf16x8 vs, vh;
            vs[0] = to_bf(sx.x); vs[1] = to_bf(sx.y); vs[2] = to_bf(sx.z); vs[3] = to_bf(sx.w);
            vs[4] = to_bf(sy.x); vs[5] = to_bf(sy.y); vs[6] = to_bf(sy.z); vs[7] = to_bf(sy.w);
            vh[0] = to_bf(hx.x); vh[1] = to_bf(hx.y); vh[2] = to_bf(hx.z); vh[3] = to_bf(hx.w);
            vh[4] = to_bf(hy.x); vh[5] = to_bf(hy.y); vh[6] = to_bf(hy.z); vh[7] = to_bf(hy.w);
            sS[kk * 256 + tid] = vs;
            sH[kk * 256 + tid] = vh;
        }
    }
    __syncthreads();
    f32x4 aa[4][4], ab[4][4];
#pragma unroll
    for (int mf = 0; mf < 4; ++mf)
#pragma unroll
        for (int nf = 0; nf < 4; ++nf) { aa[mf][nf] = (f32x4)0.f; ab[mf][nf] = (f32x4)0.f; }
#pragma unroll
    for (int kk = 0; kk < 4; ++kk) {
        bf16x8 a1[4], a2[4], bv1[4], bv2[4];
#pragma unroll
        for (int mf = 0; mf < 4; ++mf) {
            a1[mf] = sS[kk * 256 + mf * 64 + lane];
            a2[mf] = sH[kk * 256 + mf * 64 + lane];
        }
#pragma unroll
        for (int nf = 0; nf < 4; ++nf) {
            bv1[nf] = wn2f[(size_t)((wave * 4 + nf) * 4 + kk) * 64 + lane];
            bv2[nf] = wl2f[(size_t)((wave * 4 + nf) * 4 + kk) * 64 + lane];
        }
#pragma unroll
        for (int mf = 0; mf < 4; ++mf)
#pragma unroll
            for (int nf = 0; nf < 4; ++nf) {
                aa[mf][nf] = __builtin_amdgcn_mfma_f32_16x16x32_bf16(a1[mf], bv1[nf],
                                                                     aa[mf][nf], 0, 0, 0);
                ab[mf][nf] = __builtin_amdgcn_mfma_f32_16x16x32_bf16(a2[mf], bv2[nf],
                                                                     ab[mf][nf], 0, 0, 0);
            }
    }
    int gq = lane >> 4, cl = lane & 15;
    float dinv[4][4];
#pragma unroll
    for (int mf = 0; mf < 4; ++mf)
#pragma unroll
        for (int q = 0; q < 4; ++q) {
            int m = n0 + mf * 16 + gq * 4 + q;
            if (m >= NN) m = NN - 1;
            dinv[mf][q] = 1.f / fmaxf((float)cnt[m], 1.f);
        }
    float b2v[4];
#pragma unroll
    for (int nf = 0; nf < 4; ++nf) b2v[nf] = b2[wave * 64 + nf * 16 + cl];
#pragma unroll
    for (int mf = 0; mf < 4; ++mf)
#pragma unroll
        for (int nf = 0; nf < 4; ++nf) {
            int c = wave * 64 + nf * 16 + cl;
#pragma unroll
            for (int q = 0; q < 4; ++q) {
                int m = n0 + mf * 16 + gq * 4 + q;
                if (m >= NN) m = NN - 1;
                float araw = agg2[(size_t)m * 256 + c];
                aa[mf][nf][q] = fmaxf((araw + aa[mf][nf][q]) * dinv[mf][q]
                                      + ab[mf][nf][q] + b2v[nf], 0.f);
            }
        }
    __builtin_amdgcn_sched_barrier(0);
#pragma unroll
    for (int mf = 0; mf < 4; ++mf)
#pragma unroll
        for (int nf = 0; nf < 4; ++nf) {
            int c = wave * 64 + nf * 16 + cl;
#pragma unroll
            for (int q = 0; q < 4; ++q) {
                int m = n0 + mf * 16 + gq * 4 + q;
                if (m < NN) h2[(size_t)m * 256 + c] = aa[mf][nf][q];
            }
        }
}

// ---------------- per-graph max + output ----------------

__device__ __forceinline__ int lower_bound_i(const int* __restrict__ a, int n, int v) {
    int lo = 0, hi = n;
    while (lo < hi) {
        int m = (lo + hi) >> 1;
        if (a[m] < v) lo = m + 1; else hi = m;
    }
    return lo;
}

__global__ void k_gmax_nodes(const float* __restrict__ h2, const int* __restrict__ n2g,
                             float* __restrict__ gn) {
    int g = blockIdx.x, q = blockIdx.y, j = threadIdx.x;
    int lo = lower_bound_i(n2g, NN, g);
    int hi = lower_bound_i(n2g, NN, g + 1);
    float mx = 0.f;
    for (int n = lo + q; n < hi; n += 16) mx = fmaxf(mx, h2[(size_t)n * 256 + j]);
    atomicMax((int*)&gn[g * 256 + j], __float_as_int(mx));
}

__global__ void k_gmax_edges(const float* __restrict__ er2, const int* __restrict__ e2g,
                             const int* __restrict__ etype, float* __restrict__ ge) {
    int g = blockIdx.x, q = blockIdx.y, j = threadIdx.x;
    int lo = lower_bound_i(e2g, NE, g);
    int hi = lower_bound_i(e2g, NE, g + 1);
    float mx = 0.f;
    for (int e = lo + q; e < hi; e += 16) mx = fmaxf(mx, er2[etype[e] * 256 + j]);
    atomicMax((int*)&ge[g * 256 + j], __float_as_int(mx));
}

__global__ void k_out(const float* __restrict__ gn, const float* __restrict__ ge,
                      const int* __restrict__ time_idx, const int* __restrict__ lens,
                      float* __restrict__ out) {
    int idx = blockIdx.x * 256 + threadIdx.x;
    const int NOUT = BNUM * SEQL * 512;
    if (idx < NOUT) {
        int j = idx & 511;
        int bt = idx >> 9;
        int b = bt / SEQL, t = bt - b * SEQL;
        float v = 0.f;
        if (t < lens[b]) {
            int g = time_idx[bt];
            v = (j < 256) ? gn[g * 256 + j] : ge[g * 256 + (j - 256)];
        }
        out[idx] = v;
    } else if (idx < NOUT + BNUM) {
        int b = idx - NOUT;
        out[idx] = (float)lens[b];
    }
}

// ---------------- launch ----------------

extern "C" void kernel_launch(void* const* d_in, const int* in_sizes, int n_in,
                              void* d_out, int out_size, void* d_ws, size_t ws_size,
                              hipStream_t stream) {
    const int*   node_ids  = (const int*)d_in[0];
    const int*   edge_src  = (const int*)d_in[1];
    const int*   edge_dst  = (const int*)d_in[2];
    const int*   edge_type = (const int*)d_in[3];
    const int*   node2g    = (const int*)d_in[4];
    const int*   edge2g    = (const int*)d_in[5];
    const float* text_emb  = (const float*)d_in[6];
    const int*   time_idx  = (const int*)d_in[7];
    const int*   lens      = (const int*)d_in[8];
    const float* ent_emb   = (const float*)d_in[9];
    const float* ent_mem   = (const float*)d_in[10];
    const float* rel_emb   = (const float*)d_in[11];
    const float* rel_mem   = (const float*)d_in[12];
    const float* w_node_W  = (const float*)d_in[13];
    const float* w_node_b  = (const float*)d_in[14];
    const float* w_rel_W   = (const float*)d_in[15];
    const float* w_rel_b   = (const float*)d_in[16];
    const float* Wn1 = (const float*)d_in[17];
    const float* Wl1 = (const float*)d_in[18];
    const float* Wt1 = (const float*)d_in[19];
    const float* Wr1 = (const float*)d_in[20];
    const float* b1  = (const float*)d_in[21];
    const float* Wn2 = (const float*)d_in[22];
    const float* Wl2 = (const float*)d_in[23];
    const float* Wt2 = (const float*)d_in[24];
    const float* Wr2 = (const float*)d_in[25];
    const float* b2  = (const float*)d_in[26];

    float* ws = (float*)d_ws;
    size_t off = 0;
    float* rel_feat = ws + off; off += (size_t)NREL * 256;
    float* er1      = ws + off; off += (size_t)NREL * 128;
    float* er2      = ws + off; off += (size_t)NREL * 256;
    float* ecomb    = ws + off; off += (size_t)NREL * 384;
    float* ha1      = ws + off; off += (size_t)NENT * 128;
    float* hb1      = ws + off; off += (size_t)NENT * 128;
    float* cw       = ws + off; off += (size_t)768 * 256;
    float* bc       = ws + off; off += 256;
    bf16x8* wtf  = (bf16x8*)(ws + off); off += (size_t)24 * 16 * 64 * 4;  // 384KB
    bf16x8* cwf  = (bf16x8*)(ws + off); off += (size_t)16 * 24 * 64 * 4;  // 384KB
    bf16x8* wn2f = (bf16x8*)(ws + off); off += (size_t)16 * 4 * 64 * 4;   // 64KB
    bf16x8* wl2f = (bf16x8*)(ws + off); off += (size_t)16 * 4 * 64 * 4;   // 64KB
    // ---- zero region: cnt | gn | ge ----
    int*   cnt = (int*)(ws + off);
    size_t zoff = off;          off += 100096;
    float* gn  = ws + off;      off += (size_t)GNUM * 256;
    float* ge  = ws + off;      off += (size_t)GNUM * 256;
    size_t zbytes = (off - zoff) * sizeof(float);
    // ---- CSR arrays ----
    int* row_off = (int*)(ws + off); off += 100352;
    int* cur     = (int*)(ws + off); off += 100096;
    int* bsum    = (int*)(ws + off); off += 512;
    int* eidx    = (int*)(ws + off); off += (size_t)NE;
    int* esrcC   = (int*)(ws + off); off += (size_t)NE;
    int* etC     = (int*)(ws + off); off += (size_t)NE;
    int* nidC    = (int*)(ws + off); off += (size_t)NE;
    // ---- big buffers (with aliasing: s1 <- tsumb, h2 <- fold) ----
    unsigned short* tsumb = (unsigned short*)(ws + off);
    float* s1 = ws + off;                       // alias: tsumb dead before k_s1
    off += (size_t)NN * 512 / 2;                // 25.6M floats
    float* fold = ws + off;
    float* h2   = ws + off;                     // alias: fold dead before k_h2 writes
    off += (size_t)NN * 384;                    // 38.4M floats
    float* h1   = ws + off; off += (size_t)NN * 128;
    float* agg2 = ws + off; off += (size_t)NN * 256;

    hipMemsetAsync((void*)cnt, 0, zbytes, stream);

    // CSR
    k_cnt<<<(NE + 255) / 256, 256, 0, stream>>>(edge_dst, cnt);
    k_scan_blk<<<391, 256, 0, stream>>>(cnt, row_off, bsum);
    k_scan_top<<<1, 512, 0, stream>>>(bsum);
    k_scan_add<<<391, 256, 0, stream>>>(row_off, bsum, cur);
    k_fill<<<(NE + 255) / 256, 256, 0, stream>>>(edge_dst, edge_src, edge_type, node_ids,
                                                 cur, eidx, esrcC, etC, nidC);

    // relation-side (tiny)
    k_rel_feat<<<NREL, 256, 0, stream>>>(rel_emb, rel_mem, w_rel_W, w_rel_b, rel_feat);
    k_rel_l1<<<NREL, 256, 0, stream>>>(rel_feat, Wn1, Wr1, ecomb, er1);
    k_rel_l2<<<NREL, 256, 0, stream>>>(er1, Wr2, Wn2, er2, ecomb);

    // combined node weights + packing
    k_cw<<<768, 256, 0, stream>>>(w_node_W, Wn1, Wl1, cw);
    k_cb<<<1, 256, 0, stream>>>(w_node_b, Wn1, Wl1, bc);
    k_pack<<<8 * 16, 64, 0, stream>>>(Wt1, wtf, 512, 128);
    k_pack<<<16 * 16, 64, 0, stream>>>(Wt2, wtf + (size_t)8 * 16 * 64, 512, 256);
    k_pack<<<16 * 24, 64, 0, stream>>>(cw, cwf, 768, 256);
    k_pack<<<16 * 4, 64, 0, stream>>>(Wn2, wn2f, 128, 256);
    k_pack<<<16 * 4, 64, 0, stream>>>(Wl2, wl2f, 128, 256);

    // entity GEMM -> ha1, hb1
    k_ent<<<(NENT + 63) / 64, 256, 0, stream>>>(ent_emb, ent_mem, cwf, bc, ha1, hb1);

    // per-node text sum + fold sums (replaces edge GEMM's M=200k with M=100k)
    k_tsum<<<NN / 4, 256, 0, stream>>>(text_emb, row_off, eidx, etC, nidC,
                                       ha1, ecomb, tsumb, fold);

    // dense node GEMM -> h1, agg2
    k_node<<<(NN + 63) / 64, 256, 0, stream>>>(tsumb, fold, node_ids, cnt, wtf,
                                               hb1, b1, h1, agg2);

    // gather s1 (aliases tsumb region — dead now)
    k_s1<<<NN / 4, 256, 0, stream>>>(h1, row_off, esrcC, s1);
    // dual GEMM -> h2 (aliases fold region — dead now)
    k_h2<<<(NN + 63) / 64, 256, 0, stream>>>(s1, h1, agg2, cnt, wn2f, wl2f, b2, h2);

    k_gmax_nodes<<<dim3(GNUM, 16), 256, 0, stream>>>(h2, node2g, gn);
    k_gmax_edges<<<dim3(GNUM, 16), 256, 0, stream>>>(er2, edge2g, edge_type, ge);
    k_out<<<(BNUM * SEQL * 512 + BNUM + 255) / 256, 256, 0, stream>>>(gn, ge, time_idx, lens,
                                                                      (float*)d_out);
}

// Round 13
// 581.249 us; speedup vs baseline: 1.5402x; 1.5402x over previous
//
#include <hip/hip_runtime.h>

#define HD    256
#define HD2   128
#define SDIM  512
#define GNUM  64
#define NN    100000
#define NE    200000
#define NENT  20000
#define NREL  500
#define BNUM  32
#define SEQL  10

typedef __attribute__((ext_vector_type(4))) float f32x4;
typedef __attribute__((ext_vector_type(8))) short bf16x8;

__device__ __forceinline__ short to_bf(float f) {
    unsigned u = __float_as_uint(f);
    u += 0x7fff + ((u >> 16) & 1);
    return (short)(u >> 16);
}
__device__ __forceinline__ float bf_to_f(unsigned short u) {
    return __uint_as_float(((unsigned)u) << 16);
}

// ---------------- CSR build ----------------

__global__ void k_cnt(const int* __restrict__ edst, int* __restrict__ cnt) {
    int e = blockIdx.x * 256 + threadIdx.x;
    if (e < NE) atomicAdd(&cnt[edst[e]], 1);
}

__global__ void k_scan_blk(const int* __restrict__ cnt, int* __restrict__ row_off,
                           int* __restrict__ bsum) {
    __shared__ int s[256];
    int i = blockIdx.x * 256 + threadIdx.x;
    int v = cnt[i];
    s[threadIdx.x] = v;
    __syncthreads();
    for (int d = 1; d < 256; d <<= 1) {
        int t = (threadIdx.x >= d) ? s[threadIdx.x - d] : 0;
        __syncthreads();
        s[threadIdx.x] += t;
        __syncthreads();
    }
    row_off[i] = s[threadIdx.x] - v;  // exclusive
    if (threadIdx.x == 255) bsum[blockIdx.x] = s[255];
}

__global__ void k_scan_top(int* __restrict__ bsum) {  // 391 partials
    __shared__ int s[512];
    int v = (threadIdx.x < 391) ? bsum[threadIdx.x] : 0;
    s[threadIdx.x] = v;
    __syncthreads();
    for (int d = 1; d < 512; d <<= 1) {
        int t = (threadIdx.x >= d) ? s[threadIdx.x - d] : 0;
        __syncthreads();
        s[threadIdx.x] += t;
        __syncthreads();
    }
    if (threadIdx.x < 391) bsum[threadIdx.x] = s[threadIdx.x] - v;  // exclusive
}

__global__ void k_scan_add(int* __restrict__ row_off, const int* __restrict__ bsum,
                           int* __restrict__ cur) {
    int i = blockIdx.x * 256 + threadIdx.x;
    int v = row_off[i] + bsum[blockIdx.x];
    row_off[i] = v;
    cur[i] = v;
}

// CSR-ordered edge arrays
__global__ void k_fill(const int* __restrict__ edst, const int* __restrict__ esrc,
                       const int* __restrict__ etype, const int* __restrict__ node_ids,
                       int* __restrict__ cur, int* __restrict__ eidx,
                       int* __restrict__ esrcC, int* __restrict__ etC,
                       int* __restrict__ nidC) {
    int e = blockIdx.x * 256 + threadIdx.x;
    if (e < NE) {
        int pos = atomicAdd(&cur[edst[e]], 1);
        int s = esrc[e];
        eidx[pos] = e;
        esrcC[pos] = s;
        etC[pos] = etype[e];
        nidC[pos] = node_ids[s];
    }
}

// ---------------- small per-relation kernels ----------------

__global__ void k_rel_feat(const float* __restrict__ rel_emb, const float* __restrict__ rel_mem,
                           const float* __restrict__ W, const float* __restrict__ b,
                           float* __restrict__ rel_feat) {
    __shared__ float s[768];
    int r = blockIdx.x, j = threadIdx.x;
    for (int k = j; k < 768; k += 256)
        s[k] = (k < 512) ? rel_emb[r * 512 + k] : rel_mem[r * 256 + (k - 512)];
    __syncthreads();
    float acc = b[j];
    for (int k = 0; k < 768; ++k) acc += s[k] * W[k * 256 + j];
    rel_feat[r * 256 + j] = acc;
}

__global__ void k_rel_l1(const float* __restrict__ rel_feat, const float* __restrict__ Wn1,
                         const float* __restrict__ Wr1, float* __restrict__ ecomb,
                         float* __restrict__ er1) {
    __shared__ float s[256];
    int r = blockIdx.x, j = threadIdx.x;
    s[j] = rel_feat[r * 256 + j];
    __syncthreads();
    if (j < 128) {
        float acc = 0.f;
        for (int k = 0; k < 256; ++k) acc += s[k] * Wn1[k * 128 + j];
        ecomb[r * 384 + j] = acc;
    } else {
        int jj = j - 128;
        float acc = 0.f;
        for (int k = 0; k < 256; ++k) acc += s[k] * Wr1[k * 128 + jj];
        er1[r * 128 + jj] = fmaxf(acc, 0.f);
    }
}

__global__ void k_rel_l2(const float* __restrict__ er1, const float* __restrict__ Wr2,
                         const float* __restrict__ Wn2, float* __restrict__ er2,
                         float* __restrict__ ecomb) {
    __shared__ float s[128];
    int r = blockIdx.x, j = threadIdx.x;
    if (j < 128) s[j] = er1[r * 128 + j];
    __syncthreads();
    float a = 0.f, c = 0.f;
    for (int k = 0; k < 128; ++k) {
        float v = s[k];
        a += v * Wr2[k * 256 + j];
        c += v * Wn2[k * 256 + j];
    }
    er2[r * 256 + j] = fmaxf(a, 0.f);
    ecomb[r * 384 + 128 + j] = c;
}

// ---------------- combined node weights: cw = w_node_W @ [Wn1|Wl1] ----------------

__global__ void k_cw(const float* __restrict__ wnW, const float* __restrict__ Wn1,
                     const float* __restrict__ Wl1, float* __restrict__ cw) {
    __shared__ float s[256];
    int k = blockIdx.x, j = threadIdx.x;
    s[j] = wnW[k * 256 + j];
    __syncthreads();
    float acc = 0.f;
    if (j < 128) {
        for (int m = 0; m < 256; ++m) acc += s[m] * Wn1[m * 128 + j];
    } else {
        int jj = j - 128;
        for (int m = 0; m < 256; ++m) acc += s[m] * Wl1[m * 128 + jj];
    }
    cw[k * 256 + j] = acc;
}

__global__ void k_cb(const float* __restrict__ wnb, const float* __restrict__ Wn1,
                     const float* __restrict__ Wl1, float* __restrict__ bc) {
    int j = threadIdx.x;
    float acc = 0.f;
    if (j < 128) {
        for (int m = 0; m < 256; ++m) acc += wnb[m] * Wn1[m * 128 + j];
    } else {
        int jj = j - 128;
        for (int m = 0; m < 256; ++m) acc += wnb[m] * Wl1[m * 128 + jj];
    }
    bc[j] = acc;
}

// ---------------- generic weight packer: f32 [KxN] -> bf16 B-frags ----------------
__global__ void k_pack(const float* __restrict__ src, bf16x8* __restrict__ dst,
                       int K, int N) {
    int KF = K >> 5;
    int fid = blockIdx.x;
    int n = fid / KF, kk = fid - n * KF;
    int lane = threadIdx.x;
    int col = n * 16 + (lane & 15);
    int kb = kk * 32 + (lane >> 4) * 8;
    bf16x8 v;
#pragma unroll
    for (int j = 0; j < 8; ++j) v[j] = to_bf(src[(size_t)(kb + j) * N + col]);
    dst[(size_t)fid * 64 + lane] = v;
}

// ---------------- entity GEMM: [ee|em] @ cw -> ha1, hb1 ----------------

__global__ void __launch_bounds__(256) k_ent(const float* __restrict__ ee,
                                             const float* __restrict__ em,
                                             const bf16x8* __restrict__ cwf,
                                             const float* __restrict__ bc,
                                             float* __restrict__ ha1,
                                             float* __restrict__ hb1) {
    __shared__ bf16x8 sA[2048];  // 32KB
    int tid = threadIdx.x;
    int e0 = blockIdx.x * 64;
    int wave = tid >> 6, lane = tid & 63;
    int gs = (tid >> 4) & 3, rs = tid & 15;
    int rowS = ((tid >> 6) & 3) * 16 + rs;
    int ent = e0 + rowS;
    if (ent >= NENT) ent = NENT - 1;
    f32x4 acc[4][4];
#pragma unroll
    for (int mf = 0; mf < 4; ++mf)
#pragma unroll
        for (int nf = 0; nf < 4; ++nf) acc[mf][nf] = (f32x4)0.f;

    for (int ch = 0; ch < 3; ++ch) {
        if (ch) __syncthreads();
#pragma unroll
        for (int it = 0; it < 8; ++it) {
            int gc = ch * 256 + it * 32 + gs * 8;
            const float4* p = (gc < 512)
                ? (const float4*)(ee + (size_t)ent * 512 + gc)
                : (const float4*)(em + (size_t)ent * 256 + (gc - 512));
            float4 x = p[0], y = p[1];
            bf16x8 v;
            v[0] = to_bf(x.x); v[1] = to_bf(x.y); v[2] = to_bf(x.z); v[3] = to_bf(x.w);
            v[4] = to_bf(y.x); v[5] = to_bf(y.y); v[6] = to_bf(y.z); v[7] = to_bf(y.w);
            sA[it * 256 + tid] = v;
        }
        __syncthreads();
#pragma unroll
        for (int kkl = 0; kkl < 8; ++kkl) {
            bf16x8 a[4], b[4];
#pragma unroll
            for (int mf = 0; mf < 4; ++mf) a[mf] = sA[kkl * 256 + mf * 64 + lane];
#pragma unroll
            for (int nf = 0; nf < 4; ++nf)
                b[nf] = cwf[(size_t)((wave * 4 + nf) * 24 + ch * 8 + kkl) * 64 + lane];
#pragma unroll
            for (int mf = 0; mf < 4; ++mf)
#pragma unroll
                for (int nf = 0; nf < 4; ++nf)
                    acc[mf][nf] = __builtin_amdgcn_mfma_f32_16x16x32_bf16(a[mf], b[nf],
                                                                          acc[mf][nf], 0, 0, 0);
        }
    }
    int gq = lane >> 4, cl = lane & 15;
#pragma unroll
    for (int mf = 0; mf < 4; ++mf)
#pragma unroll
        for (int nf = 0; nf < 4; ++nf) {
            int c = wave * 64 + nf * 16 + cl;
            float bb = bc[c];
#pragma unroll
            for (int q = 0; q < 4; ++q) {
                int m = e0 + mf * 16 + gq * 4 + q;
                if (m < NENT) {
                    float val = acc[mf][nf][q] + bb;
                    if (c < 128) ha1[(size_t)m * 128 + c] = val;
                    else hb1[(size_t)m * 128 + (c - 128)] = val;
                }
            }
        }
}

// ---------------- edge GEMM: PURE streaming (sequential read AND write) ----------------

__global__ void __launch_bounds__(256, 2) k_edge(const float* __restrict__ text,
                                                 const bf16x8* __restrict__ wtf,
                                                 unsigned short* __restrict__ msg) {
    __shared__ bf16x8 sA[4096];  // 64KB: full 64x512 bf16 A-tile in frag order
    int tid = threadIdx.x;
    size_t e0 = (size_t)blockIdx.x * 64;
    int R = ((tid >> 6) << 4) + (tid & 15);
    int g = (tid >> 4) & 3;
    const float* trow = text + (e0 + R) * 512 + g * 8;

    float4 xv[16], yv[16];
#pragma unroll
    for (int kk = 0; kk < 16; ++kk) {
        const float4* p = (const float4*)(trow + kk * 32);
        xv[kk] = p[0];
        yv[kk] = p[1];
    }
#pragma unroll
    for (int kk = 0; kk < 16; ++kk) {
        bf16x8 v;
        v[0] = to_bf(xv[kk].x); v[1] = to_bf(xv[kk].y);
        v[2] = to_bf(xv[kk].z); v[3] = to_bf(xv[kk].w);
        v[4] = to_bf(yv[kk].x); v[5] = to_bf(yv[kk].y);
        v[6] = to_bf(yv[kk].z); v[7] = to_bf(yv[kk].w);
        sA[kk * 256 + tid] = v;
    }
    __syncthreads();

    int wave = tid >> 6, lane = tid & 63;
    f32x4 acc[4][6];
#pragma unroll
    for (int mf = 0; mf < 4; ++mf)
#pragma unroll
        for (int nf = 0; nf < 6; ++nf) acc[mf][nf] = (f32x4)0.f;

#pragma unroll
    for (int kk = 0; kk < 16; ++kk) {
        bf16x8 a[4], b[6];
#pragma unroll
        for (int mf = 0; mf < 4; ++mf) a[mf] = sA[kk * 256 + mf * 64 + lane];
#pragma unroll
        for (int nf = 0; nf < 6; ++nf)
            b[nf] = wtf[(size_t)((wave * 6 + nf) * 16 + kk) * 64 + lane];
#pragma unroll
        for (int mf = 0; mf < 4; ++mf)
#pragma unroll
            for (int nf = 0; nf < 6; ++nf)
                acc[mf][nf] = __builtin_amdgcn_mfma_f32_16x16x32_bf16(a[mf], b[nf],
                                                                      acc[mf][nf], 0, 0, 0);
    }

    int gq = lane >> 4, cl = lane & 15;
#pragma unroll
    for (int mf = 0; mf < 4; ++mf)
#pragma unroll
        for (int nf = 0; nf < 6; ++nf) {
            int c = wave * 96 + nf * 16 + cl;
            f32x4 v = acc[mf][nf];
#pragma unroll
            for (int q = 0; q < 4; ++q) {
                int row = mf * 16 + gq * 4 + q;
                msg[(e0 + row) * 384 + c] = (unsigned short)to_bf(v[q]);
            }
        }
}

// ---------------- k_agg: CSR gather of msg rows + per-edge table folds -> h1b, agg2b ----------------

__global__ void __launch_bounds__(256) k_agg(const unsigned short* __restrict__ msg,
                                             const int* __restrict__ row_off,
                                             const int* __restrict__ eidx,
                                             const int* __restrict__ etC,
                                             const int* __restrict__ nidC,
                                             const int* __restrict__ node_ids,
                                             const float* __restrict__ ha1,
                                             const float* __restrict__ ecomb,
                                             const float* __restrict__ hb1,
                                             const float* __restrict__ b1,
                                             unsigned short* __restrict__ h1b,
                                             unsigned short* __restrict__ agg2b) {
    int n = blockIdx.x * 4 + (threadIdx.x >> 6);
    int lane = threadIdx.x & 63;
    if (n >= NN) return;
    int beg = row_off[n], end = row_off[n + 1];
    float d = fmaxf((float)(end - beg), 1.f);
    int nid0 = node_ids[n];
    int c = lane * 2;
    float a0 = 0.f, a1 = 0.f, a2 = 0.f, a3 = 0.f, a4 = 0.f, a5 = 0.f;
    const unsigned* m32 = (const unsigned*)msg;
    for (int i = beg; i < end; ++i) {
        size_t e = (size_t)eidx[i];
        int et = etC[i], nid = nidC[i];
        size_t base = e * 192;
        unsigned u0 = m32[base + lane];
        unsigned u1 = m32[base + 64 + lane];
        unsigned u2 = m32[base + 128 + lane];
        const float2 ec0 = *(const float2*)(ecomb + (size_t)et * 384 + c);
        const float2 ec1 = *(const float2*)(ecomb + (size_t)et * 384 + 128 + c);
        const float2 ec2 = *(const float2*)(ecomb + (size_t)et * 384 + 256 + c);
        const float2 hv = *(const float2*)(ha1 + (size_t)nid * 128 + c);
        a0 += bf_to_f((unsigned short)(u0 & 0xffff)) + hv.x - ec0.x;
        a1 += bf_to_f((unsigned short)(u0 >> 16)) + hv.y - ec0.y;
        a2 += bf_to_f((unsigned short)(u1 & 0xffff)) - ec1.x;
        a3 += bf_to_f((unsigned short)(u1 >> 16)) - ec1.y;
        a4 += bf_to_f((unsigned short)(u2 & 0xffff)) - ec2.x;
        a5 += bf_to_f((unsigned short)(u2 >> 16)) - ec2.y;
    }
    const float2 hb = *(const float2*)(hb1 + (size_t)nid0 * 128 + c);
    const float2 bb = *(const float2*)(b1 + c);
    float hx = fmaxf(a0 / d + hb.x + bb.x, 0.f);
    float hy = fmaxf(a1 / d + hb.y + bb.y, 0.f);
    unsigned hp = ((unsigned)(unsigned short)to_bf(hx)) |
                  (((unsigned)(unsigned short)to_bf(hy)) << 16);
    ((unsigned*)h1b)[(size_t)n * 64 + lane] = hp;
    unsigned g0 = ((unsigned)(unsigned short)to_bf(a2)) |
                  (((unsigned)(unsigned short)to_bf(a3)) << 16);
    unsigned g1 = ((unsigned)(unsigned short)to_bf(a4)) |
                  (((unsigned)(unsigned short)to_bf(a5)) << 16);
    ((unsigned*)agg2b)[(size_t)n * 128 + lane] = g0;
    ((unsigned*)agg2b)[(size_t)n * 128 + 64 + lane] = g1;
}

// ---------------- k_s1: s1[n] = sum over incoming edges of h1[src] (bf16 in, f32 out) ----------------

__global__ void __launch_bounds__(256) k_s1(const unsigned short* __restrict__ h1b,
                                            const int* __restrict__ row_off,
                                            const int* __restrict__ esrcC,
                                            float* __restrict__ s1) {
    int n = blockIdx.x * 4 + (threadIdx.x >> 6);
    int lane = threadIdx.x & 63;
    if (n >= NN) return;
    int beg = row_off[n], end = row_off[n + 1];
    float2 acc; acc.x = 0.f; acc.y = 0.f;
    const unsigned* h32 = (const unsigned*)h1b;
    for (int i = beg; i < end; ++i) {
        int src = esrcC[i];
        unsigned u = h32[(size_t)src * 64 + lane];
        acc.x += bf_to_f((unsigned short)(u & 0xffff));
        acc.y += bf_to_f((unsigned short)(u >> 16));
    }
    ((float2*)(s1 + (size_t)n * 128))[lane] = acc;
}

// ---------------- h2 dual GEMM + fused per-graph max -> gn (no h2 buffer) ----------------

__global__ void __launch_bounds__(256) k_h2(const float* __restrict__ s1,
                                            const unsigned short* __restrict__ h1b,
                                            const unsigned short* __restrict__ agg2b,
                                            const int* __restrict__ cnt,
                                            const int* __restrict__ n2g,
                                            const bf16x8* __restrict__ wn2f,
                                            const bf16x8* __restrict__ wl2f,
                                            const float* __restrict__ b2,
                                            float* __restrict__ gn) {
    __shared__ bf16x8 sS[1024], sH[1024];  // 16KB each
    __shared__ int s_g[64];
    int tid = threadIdx.x, n0 = blockIdx.x * 64;
    int wave = tid >> 6, lane = tid & 63;
    if (tid < 64) {
        int m = n0 + tid;
        if (m >= NN) m = NN - 1;
        s_g[tid] = n2g[m];
    }
    {
        int gsv = (tid >> 4) & 3, rsv = tid & 15;
        int row = ((tid >> 6) & 3) * 16 + rsv;
        int m = n0 + row;
        if (m >= NN) m = NN - 1;
#pragma unroll
        for (int kk = 0; kk < 4; ++kk) {
            int cb = kk * 32 + gsv * 8;
            const float4* ps = (const float4*)(s1 + (size_t)m * 128 + cb);
            float4 sx = ps[0], sy = ps[1];
            bf16x8 vs;
            vs[0] = to_bf(sx.x); vs[1] = to_bf(sx.y); vs[2] = to_bf(sx.z); vs[3] = to_bf(sx.w);
            vs[4] = to_bf(sy.x); vs[5] = to_bf(sy.y); vs[6] = to_bf(sy.z); vs[7] = to_bf(sy.w);
            bf16x8 vh = *(const bf16x8*)(h1b + (size_t)m * 128 + cb);
            sS[kk * 256 + tid] = vs;
            sH[kk * 256 + tid] = vh;
        }
    }
    __syncthreads();
    f32x4 aa[4][4], ab[4][4];
#pragma unroll
    for (int mf = 0; mf < 4; ++mf)
#pragma unroll
        for (int nf = 0; nf < 4; ++nf) { aa[mf][nf] = (f32x4)0.f; ab[mf][nf] = (f32x4)0.f; }
#pragma unroll
    for (int kk = 0; kk < 4; ++kk) {
        bf16x8 a1[4], a2[4], bv1[4], bv2[4];
#pragma unroll
        for (int mf = 0; mf < 4; ++mf) {
            a1[mf] = sS[kk * 256 + mf * 64 + lane];
            a2[mf] = sH[kk * 256 + mf * 64 + lane];
        }
#pragma unroll
        for (int nf = 0; nf < 4; ++nf) {
            bv1[nf] = wn2f[(size_t)((wave * 4 + nf) * 4 + kk) * 64 + lane];
            bv2[nf] = wl2f[(size_t)((wave * 4 + nf) * 4 + kk) * 64 + lane];
        }
#pragma unroll
        for (int mf = 0; mf < 4; ++mf)
#pragma unroll
            for (int nf = 0; nf < 4; ++nf) {
                aa[mf][nf] = __builtin_amdgcn_mfma_f32_16x16x32_bf16(a1[mf], bv1[nf],
                                                                     aa[mf][nf], 0, 0, 0);
                ab[mf][nf] = __builtin_amdgcn_mfma_f32_16x16x32_bf16(a2[mf], bv2[nf],
                                                                     ab[mf][nf], 0, 0, 0);
            }
    }
    int gq = lane >> 4, cl = lane & 15;
    float dinv[4][4];
#pragma unroll
    for (int mf = 0; mf < 4; ++mf)
#pragma unroll
        for (int q = 0; q < 4; ++q) {
            int m = n0 + mf * 16 + gq * 4 + q;
            if (m >= NN) m = NN - 1;
            dinv[mf][q] = 1.f / fmaxf((float)cnt[m], 1.f);
        }
    float b2v[4];
#pragma unroll
    for (int nf = 0; nf < 4; ++nf) b2v[nf] = b2[wave * 64 + nf * 16 + cl];
#pragma unroll
    for (int mf = 0; mf < 4; ++mf)
#pragma unroll
        for (int nf = 0; nf < 4; ++nf) {
            int c = wave * 64 + nf * 16 + cl;
#pragma unroll
            for (int q = 0; q < 4; ++q) {
                int m = n0 + mf * 16 + gq * 4 + q;
                if (m >= NN) m = NN - 1;
                float araw = bf_to_f(agg2b[(size_t)m * 256 + c]);
                aa[mf][nf][q] = fmaxf((araw + aa[mf][nf][q]) * dinv[mf][q]
                                      + ab[mf][nf][q] + b2v[nf], 0.f);
            }
        }
    // -------- fused per-graph max --------
    int g0 = s_g[0], g63 = s_g[63];
    if (g0 == g63) {
        // single graph (common): reduce 16 in-thread rows, then across gq lanes
#pragma unroll
        for (int nf = 0; nf < 4; ++nf) {
            float mx = 0.f;
#pragma unroll
            for (int mf = 0; mf < 4; ++mf)
#pragma unroll
                for (int q = 0; q < 4; ++q) mx = fmaxf(mx, aa[mf][nf][q]);
            mx = fmaxf(mx, __shfl_xor(mx, 16));
            mx = fmaxf(mx, __shfl_xor(mx, 32));
            if (gq == 0) {
                int c = wave * 64 + nf * 16 + cl;
                atomicMax((int*)&gn[(size_t)g0 * 256 + c], __float_as_int(mx));
            }
        }
    } else {
        // graph boundary block (rare): per-element
#pragma unroll
        for (int mf = 0; mf < 4; ++mf)
#pragma unroll
            for (int q = 0; q < 4; ++q) {
                int row = mf * 16 + gq * 4 + q;
                int m = n0 + row;
                if (m >= NN) continue;
                int gg = s_g[row];
#pragma unroll
                for (int nf = 0; nf < 4; ++nf) {
                    int c = wave * 64 + nf * 16 + cl;
                    atomicMax((int*)&gn[(size_t)gg * 256 + c],
                              __float_as_int(aa[mf][nf][q]));
                }
            }
    }
}

// ---------------- per-graph edge max + output ----------------

__device__ __forceinline__ int lower_bound_i(const int* __restrict__ a, int n, int v) {
    int lo = 0, hi = n;
    while (lo < hi) {
        int m = (lo + hi) >> 1;
        if (a[m] < v) lo = m + 1; else hi = m;
    }
    return lo;
}

__global__ void k_gmax_edges(const float* __restrict__ er2, const int* __restrict__ e2g,
                             const int* __restrict__ etype, float* __restrict__ ge) {
    int g = blockIdx.x, q = blockIdx.y, j = threadIdx.x;
    int lo = lower_bound_i(e2g, NE, g);
    int hi = lower_bound_i(e2g, NE, g + 1);
    float mx = 0.f;
    for (int e = lo + q; e < hi; e += 16) mx = fmaxf(mx, er2[etype[e] * 256 + j]);
    atomicMax((int*)&ge[g * 256 + j], __float_as_int(mx));
}

__global__ void k_out(const float* __restrict__ gn, const float* __restrict__ ge,
                      const int* __restrict__ time_idx, const int* __restrict__ lens,
                      float* __restrict__ out) {
    int idx = blockIdx.x * 256 + threadIdx.x;
    const int NOUT = BNUM * SEQL * 512;
    if (idx < NOUT) {
        int j = idx & 511;
        int bt = idx >> 9;
        int b = bt / SEQL, t = bt - b * SEQL;
        float v = 0.f;
        if (t < lens[b]) {
            int g = time_idx[bt];
            v = (j < 256) ? gn[g * 256 + j] : ge[g * 256 + (j - 256)];
        }
        out[idx] = v;
    } else if (idx < NOUT + BNUM) {
        int b = idx - NOUT;
        out[idx] = (float)lens[b];
    }
}

// ---------------- launch ----------------

extern "C" void kernel_launch(void* const* d_in, const int* in_sizes, int n_in,
                              void* d_out, int out_size, void* d_ws, size_t ws_size,
                              hipStream_t stream) {
    const int*   node_ids  = (const int*)d_in[0];
    const int*   edge_src  = (const int*)d_in[1];
    const int*   edge_dst  = (const int*)d_in[2];
    const int*   edge_type = (const int*)d_in[3];
    const int*   node2g    = (const int*)d_in[4];
    const int*   edge2g    = (const int*)d_in[5];
    const float* text_emb  = (const float*)d_in[6];
    const int*   time_idx  = (const int*)d_in[7];
    const int*   lens      = (const int*)d_in[8];
    const float* ent_emb   = (const float*)d_in[9];
    const float* ent_mem   = (const float*)d_in[10];
    const float* rel_emb   = (const float*)d_in[11];
    const float* rel_mem   = (const float*)d_in[12];
    const float* w_node_W  = (const float*)d_in[13];
    const float* w_node_b  = (const float*)d_in[14];
    const float* w_rel_W   = (const float*)d_in[15];
    const float* w_rel_b   = (const float*)d_in[16];
    const float* Wn1 = (const float*)d_in[17];
    const float* Wl1 = (const float*)d_in[18];
    const float* Wt1 = (const float*)d_in[19];
    const float* Wr1 = (const float*)d_in[20];
    const float* b1  = (const float*)d_in[21];
    const float* Wn2 = (const float*)d_in[22];
    const float* Wl2 = (const float*)d_in[23];
    const float* Wt2 = (const float*)d_in[24];
    const float* Wr2 = (const float*)d_in[25];
    const float* b2  = (const float*)d_in[26];

    float* ws = (float*)d_ws;
    size_t off = 0;
    float* rel_feat = ws + off; off += (size_t)NREL * 256;
    float* er1      = ws + off; off += (size_t)NREL * 128;
    float* er2      = ws + off; off += (size_t)NREL * 256;
    float* ecomb    = ws + off; off += (size_t)NREL * 384;
    float* ha1      = ws + off; off += (size_t)NENT * 128;
    float* hb1      = ws + off; off += (size_t)NENT * 128;
    float* cw       = ws + off; off += (size_t)768 * 256;
    float* bc       = ws + off; off += 256;
    bf16x8* wtf  = (bf16x8*)(ws + off); off += (size_t)24 * 16 * 64 * 4;  // 384KB
    bf16x8* cwf  = (bf16x8*)(ws + off); off += (size_t)16 * 24 * 64 * 4;  // 384KB
    bf16x8* wn2f = (bf16x8*)(ws + off); off += (size_t)16 * 4 * 64 * 4;   // 64KB
    bf16x8* wl2f = (bf16x8*)(ws + off); off += (size_t)16 * 4 * 64 * 4;   // 64KB
    // ---- zero region: cnt | gn | ge ----
    int*   cnt = (int*)(ws + off);
    size_t zoff = off;          off += 100096;
    float* gn  = ws + off;      off += (size_t)GNUM * 256;
    float* ge  = ws + off;      off += (size_t)GNUM * 256;
    size_t zbytes = (off - zoff) * sizeof(float);
    // ---- CSR arrays ----
    int* row_off = (int*)(ws + off); off += 100352;
    int* cur     = (int*)(ws + off); off += 100096;
    int* bsum    = (int*)(ws + off); off += 512;
    int* eidx    = (int*)(ws + off); off += (size_t)NE;
    int* esrcC   = (int*)(ws + off); off += (size_t)NE;
    int* etC     = (int*)(ws + off); off += (size_t)NE;
    int* nidC    = (int*)(ws + off); off += (size_t)NE;
    // ---- big buffers ----
    unsigned short* msg = (unsigned short*)(ws + off);
    float* s1 = ws + off;                      // s1 aliases msg (msg dead before k_s1 runs)
    off += (size_t)NE * 384 / 2;
    unsigned short* h1b   = (unsigned short*)(ws + off); off += (size_t)NN * 64;
    unsigned short* agg2b = (unsigned short*)(ws + off); off += (size_t)NN * 128;

    hipMemsetAsync((void*)cnt, 0, zbytes, stream);

    // CSR
    k_cnt<<<(NE + 255) / 256, 256, 0, stream>>>(edge_dst, cnt);
    k_scan_blk<<<391, 256, 0, stream>>>(cnt, row_off, bsum);
    k_scan_top<<<1, 512, 0, stream>>>(bsum);
    k_scan_add<<<391, 256, 0, stream>>>(row_off, bsum, cur);
    k_fill<<<(NE + 255) / 256, 256, 0, stream>>>(edge_dst, edge_src, edge_type, node_ids,
                                                 cur, eidx, esrcC, etC, nidC);

    // relation-side (tiny)
    k_rel_feat<<<NREL, 256, 0, stream>>>(rel_emb, rel_mem, w_rel_W, w_rel_b, rel_feat);
    k_rel_l1<<<NREL, 256, 0, stream>>>(rel_feat, Wn1, Wr1, ecomb, er1);
    k_rel_l2<<<NREL, 256, 0, stream>>>(er1, Wr2, Wn2, er2, ecomb);

    // combined node weights + packing
    k_cw<<<768, 256, 0, stream>>>(w_node_W, Wn1, Wl1, cw);
    k_cb<<<1, 256, 0, stream>>>(w_node_b, Wn1, Wl1, bc);
    k_pack<<<8 * 16, 64, 0, stream>>>(Wt1, wtf, 512, 128);
    k_pack<<<16 * 16, 64, 0, stream>>>(Wt2, wtf + (size_t)8 * 16 * 64, 512, 256);
    k_pack<<<16 * 24, 64, 0, stream>>>(cw, cwf, 768, 256);
    k_pack<<<16 * 4, 64, 0, stream>>>(Wn2, wn2f, 128, 256);
    k_pack<<<16 * 4, 64, 0, stream>>>(Wl2, wl2f, 128, 256);

    // entity GEMM -> ha1, hb1
    k_ent<<<(NENT + 63) / 64, 256, 0, stream>>>(ent_emb, ent_mem, cwf, bc, ha1, hb1);

    // edge GEMM: pure streaming -> msg
    k_edge<<<NE / 64, 256, 0, stream>>>(text_emb, wtf, msg);

    // CSR gather + fold -> h1b, agg2b (bf16)
    k_agg<<<NN / 4, 256, 0, stream>>>(msg, row_off, eidx, etC, nidC, node_ids,
                                      ha1, ecomb, hb1, b1, h1b, agg2b);
    // gather s1 (aliases msg region — msg dead now)
    k_s1<<<NN / 4, 256, 0, stream>>>(h1b, row_off, esrcC, s1);
    // dual GEMM + fused per-graph node max -> gn
    k_h2<<<(NN + 63) / 64, 256, 0, stream>>>(s1, h1b, agg2b, cnt, node2g,
                                             wn2f, wl2f, b2, gn);

    k_gmax_edges<<<dim3(GNUM, 16), 256, 0, stream>>>(er2, edge2g, edge_type, ge);
    k_out<<<(BNUM * SEQL * 512 + BNUM + 255) / 256, 256, 0, stream>>>(gn, ge, time_idx, lens,
                                                                      (float*)d_out);
}

// Round 14
// 580.481 us; speedup vs baseline: 1.5422x; 1.0013x over previous
//
#include <hip/hip_runtime.h>

#define HD    256
#define HD2   128
#define SDIM  512
#define GNUM  64
#define NN    100000
#define NE    200000
#define NENT  20000
#define NREL  500
#define BNUM  32
#define SEQL  10

typedef __attribute__((ext_vector_type(4))) float f32x4;
typedef __attribute__((ext_vector_type(8))) short bf16x8;

__device__ __forceinline__ short to_bf(float f) {
    unsigned u = __float_as_uint(f);
    u += 0x7fff + ((u >> 16) & 1);
    return (short)(u >> 16);
}
__device__ __forceinline__ float bf_to_f(unsigned short u) {
    return __uint_as_float(((unsigned)u) << 16);
}

// ---------------- CSR build ----------------

__global__ void k_cnt(const int* __restrict__ edst, int* __restrict__ cnt) {
    int e = blockIdx.x * 256 + threadIdx.x;
    if (e < NE) atomicAdd(&cnt[edst[e]], 1);
}

__global__ void k_scan_blk(const int* __restrict__ cnt, int* __restrict__ row_off,
                           int* __restrict__ bsum) {
    __shared__ int s[256];
    int i = blockIdx.x * 256 + threadIdx.x;
    int v = cnt[i];
    s[threadIdx.x] = v;
    __syncthreads();
    for (int d = 1; d < 256; d <<= 1) {
        int t = (threadIdx.x >= d) ? s[threadIdx.x - d] : 0;
        __syncthreads();
        s[threadIdx.x] += t;
        __syncthreads();
    }
    row_off[i] = s[threadIdx.x] - v;  // exclusive
    if (threadIdx.x == 255) bsum[blockIdx.x] = s[255];
}

__global__ void k_scan_top(int* __restrict__ bsum) {  // 391 partials
    __shared__ int s[512];
    int v = (threadIdx.x < 391) ? bsum[threadIdx.x] : 0;
    s[threadIdx.x] = v;
    __syncthreads();
    for (int d = 1; d < 512; d <<= 1) {
        int t = (threadIdx.x >= d) ? s[threadIdx.x - d] : 0;
        __syncthreads();
        s[threadIdx.x] += t;
        __syncthreads();
    }
    if (threadIdx.x < 391) bsum[threadIdx.x] = s[threadIdx.x] - v;  // exclusive
}

__global__ void k_scan_add(int* __restrict__ row_off, const int* __restrict__ bsum,
                           int* __restrict__ cur) {
    int i = blockIdx.x * 256 + threadIdx.x;
    int v = row_off[i] + bsum[blockIdx.x];
    row_off[i] = v;
    cur[i] = v;
}

// pinv[e] = CSR position of edge e; CSR-ordered esrcC/etC/nidC
__global__ void k_fill(const int* __restrict__ edst, const int* __restrict__ esrc,
                       const int* __restrict__ etype, const int* __restrict__ node_ids,
                       int* __restrict__ cur, int* __restrict__ pinv,
                       int* __restrict__ esrcC, int* __restrict__ etC,
                       int* __restrict__ nidC) {
    int e = blockIdx.x * 256 + threadIdx.x;
    if (e < NE) {
        int pos = atomicAdd(&cur[edst[e]], 1);
        int s = esrc[e];
        pinv[e] = pos;
        esrcC[pos] = s;
        etC[pos] = etype[e];
        nidC[pos] = node_ids[s];
    }
}

// ---------------- small per-relation kernels ----------------

__global__ void k_rel_feat(const float* __restrict__ rel_emb, const float* __restrict__ rel_mem,
                           const float* __restrict__ W, const float* __restrict__ b,
                           float* __restrict__ rel_feat) {
    __shared__ float s[768];
    int r = blockIdx.x, j = threadIdx.x;
    for (int k = j; k < 768; k += 256)
        s[k] = (k < 512) ? rel_emb[r * 512 + k] : rel_mem[r * 256 + (k - 512)];
    __syncthreads();
    float acc = b[j];
    for (int k = 0; k < 768; ++k) acc += s[k] * W[k * 256 + j];
    rel_feat[r * 256 + j] = acc;
}

__global__ void k_rel_l1(const float* __restrict__ rel_feat, const float* __restrict__ Wn1,
                         const float* __restrict__ Wr1, float* __restrict__ ecomb,
                         float* __restrict__ er1) {
    __shared__ float s[256];
    int r = blockIdx.x, j = threadIdx.x;
    s[j] = rel_feat[r * 256 + j];
    __syncthreads();
    if (j < 128) {
        float acc = 0.f;
        for (int k = 0; k < 256; ++k) acc += s[k] * Wn1[k * 128 + j];
        ecomb[r * 384 + j] = acc;
    } else {
        int jj = j - 128;
        float acc = 0.f;
        for (int k = 0; k < 256; ++k) acc += s[k] * Wr1[k * 128 + jj];
        er1[r * 128 + jj] = fmaxf(acc, 0.f);
    }
}

__global__ void k_rel_l2(const float* __restrict__ er1, const float* __restrict__ Wr2,
                         const float* __restrict__ Wn2, float* __restrict__ er2,
                         float* __restrict__ ecomb) {
    __shared__ float s[128];
    int r = blockIdx.x, j = threadIdx.x;
    if (j < 128) s[j] = er1[r * 128 + j];
    __syncthreads();
    float a = 0.f, c = 0.f;
    for (int k = 0; k < 128; ++k) {
        float v = s[k];
        a += v * Wr2[k * 256 + j];
        c += v * Wn2[k * 256 + j];
    }
    er2[r * 256 + j] = fmaxf(a, 0.f);
    ecomb[r * 384 + 128 + j] = c;
}

// ---------------- combined node weights: cw = w_node_W @ [Wn1|Wl1] ----------------

__global__ void k_cw(const float* __restrict__ wnW, const float* __restrict__ Wn1,
                     const float* __restrict__ Wl1, float* __restrict__ cw) {
    __shared__ float s[256];
    int k = blockIdx.x, j = threadIdx.x;
    s[j] = wnW[k * 256 + j];
    __syncthreads();
    float acc = 0.f;
    if (j < 128) {
        for (int m = 0; m < 256; ++m) acc += s[m] * Wn1[m * 128 + j];
    } else {
        int jj = j - 128;
        for (int m = 0; m < 256; ++m) acc += s[m] * Wl1[m * 128 + jj];
    }
    cw[k * 256 + j] = acc;
}

__global__ void k_cb(const float* __restrict__ wnb, const float* __restrict__ Wn1,
                     const float* __restrict__ Wl1, float* __restrict__ bc) {
    int j = threadIdx.x;
    float acc = 0.f;
    if (j < 128) {
        for (int m = 0; m < 256; ++m) acc += wnb[m] * Wn1[m * 128 + j];
    } else {
        int jj = j - 128;
        for (int m = 0; m < 256; ++m) acc += wnb[m] * Wl1[m * 128 + jj];
    }
    bc[j] = acc;
}

// ---------------- generic weight packer: f32 [KxN] -> bf16 B-frags ----------------
__global__ void k_pack(const float* __restrict__ src, bf16x8* __restrict__ dst,
                       int K, int N) {
    int KF = K >> 5;
    int fid = blockIdx.x;
    int n = fid / KF, kk = fid - n * KF;
    int lane = threadIdx.x;
    int col = n * 16 + (lane & 15);
    int kb = kk * 32 + (lane >> 4) * 8;
    bf16x8 v;
#pragma unroll
    for (int j = 0; j < 8; ++j) v[j] = to_bf(src[(size_t)(kb + j) * N + col]);
    dst[(size_t)fid * 64 + lane] = v;
}

// ---------------- entity GEMM: [ee|em] @ cw -> ha1, hb1 ----------------

__global__ void __launch_bounds__(256) k_ent(const float* __restrict__ ee,
                                             const float* __restrict__ em,
                                             const bf16x8* __restrict__ cwf,
                                             const float* __restrict__ bc,
                                             float* __restrict__ ha1,
                                             float* __restrict__ hb1) {
    __shared__ bf16x8 sA[2048];  // 32KB
    int tid = threadIdx.x;
    int e0 = blockIdx.x * 64;
    int wave = tid >> 6, lane = tid & 63;
    int gs = (tid >> 4) & 3, rs = tid & 15;
    int rowS = ((tid >> 6) & 3) * 16 + rs;
    int ent = e0 + rowS;
    if (ent >= NENT) ent = NENT - 1;
    f32x4 acc[4][4];
#pragma unroll
    for (int mf = 0; mf < 4; ++mf)
#pragma unroll
        for (int nf = 0; nf < 4; ++nf) acc[mf][nf] = (f32x4)0.f;

    for (int ch = 0; ch < 3; ++ch) {
        if (ch) __syncthreads();
#pragma unroll
        for (int it = 0; it < 8; ++it) {
            int gc = ch * 256 + it * 32 + gs * 8;
            const float4* p = (gc < 512)
                ? (const float4*)(ee + (size_t)ent * 512 + gc)
                : (const float4*)(em + (size_t)ent * 256 + (gc - 512));
            float4 x = p[0], y = p[1];
            bf16x8 v;
            v[0] = to_bf(x.x); v[1] = to_bf(x.y); v[2] = to_bf(x.z); v[3] = to_bf(x.w);
            v[4] = to_bf(y.x); v[5] = to_bf(y.y); v[6] = to_bf(y.z); v[7] = to_bf(y.w);
            sA[it * 256 + tid] = v;
        }
        __syncthreads();
#pragma unroll
        for (int kkl = 0; kkl < 8; ++kkl) {
            bf16x8 a[4], b[4];
#pragma unroll
            for (int mf = 0; mf < 4; ++mf) a[mf] = sA[kkl * 256 + mf * 64 + lane];
#pragma unroll
            for (int nf = 0; nf < 4; ++nf)
                b[nf] = cwf[(size_t)((wave * 4 + nf) * 24 + ch * 8 + kkl) * 64 + lane];
#pragma unroll
            for (int mf = 0; mf < 4; ++mf)
#pragma unroll
                for (int nf = 0; nf < 4; ++nf)
                    acc[mf][nf] = __builtin_amdgcn_mfma_f32_16x16x32_bf16(a[mf], b[nf],
                                                                          acc[mf][nf], 0, 0, 0);
        }
    }
    int gq = lane >> 4, cl = lane & 15;
#pragma unroll
    for (int mf = 0; mf < 4; ++mf)
#pragma unroll
        for (int nf = 0; nf < 4; ++nf) {
            int c = wave * 64 + nf * 16 + cl;
            float bb = bc[c];
#pragma unroll
            for (int q = 0; q < 4; ++q) {
                int m = e0 + mf * 16 + gq * 4 + q;
                if (m < NENT) {
                    float val = acc[mf][nf][q] + bb;
                    if (c < 128) ha1[(size_t)m * 128 + c] = val;
                    else hb1[(size_t)m * 128 + (c - 128)] = val;
                }
            }
        }
}

// ---------------- edge GEMM: 2-phase 32KB LDS, streaming read, CSR-scatter write ----------------

__global__ void __launch_bounds__(256, 3) k_edge(const float* __restrict__ text,
                                                 const int* __restrict__ pinv,
                                                 const bf16x8* __restrict__ wtf,
                                                 unsigned short* __restrict__ msg) {
    __shared__ bf16x8 sA[2048];  // 32KB: 64 rows x 256 k (one K-half), frag order
    __shared__ int s_pos[64];
    int tid = threadIdx.x;
    size_t e0 = (size_t)blockIdx.x * 64;
    if (tid < 64) s_pos[tid] = pinv[e0 + tid];
    int R = ((tid >> 6) << 4) + (tid & 15);
    int g = (tid >> 4) & 3;
    const float* trow = text + (e0 + R) * 512 + g * 8;

    int wave = tid >> 6, lane = tid & 63;
    f32x4 acc[4][6];
#pragma unroll
    for (int mf = 0; mf < 4; ++mf)
#pragma unroll
        for (int nf = 0; nf < 6; ++nf) acc[mf][nf] = (f32x4)0.f;

#pragma unroll
    for (int p = 0; p < 2; ++p) {
        if (p) __syncthreads();  // prior phase's LDS reads complete
#pragma unroll
        for (int h = 0; h < 2; ++h) {
            float4 xs[4], ys[4];
#pragma unroll
            for (int k2 = 0; k2 < 4; ++k2) {
                const float4* p4 = (const float4*)(trow + p * 256 + (h * 4 + k2) * 32);
                xs[k2] = p4[0];
                ys[k2] = p4[1];
            }
#pragma unroll
            for (int k2 = 0; k2 < 4; ++k2) {
                bf16x8 v;
                v[0] = to_bf(xs[k2].x); v[1] = to_bf(xs[k2].y);
                v[2] = to_bf(xs[k2].z); v[3] = to_bf(xs[k2].w);
                v[4] = to_bf(ys[k2].x); v[5] = to_bf(ys[k2].y);
                v[6] = to_bf(ys[k2].z); v[7] = to_bf(ys[k2].w);
                sA[(h * 4 + k2) * 256 + tid] = v;
            }
        }
        __syncthreads();
#pragma unroll
        for (int kkl = 0; kkl < 8; ++kkl) {
            bf16x8 a[4], b[6];
#pragma unroll
            for (int mf = 0; mf < 4; ++mf) a[mf] = sA[kkl * 256 + mf * 64 + lane];
#pragma unroll
            for (int nf = 0; nf < 6; ++nf)
                b[nf] = wtf[(size_t)((wave * 6 + nf) * 16 + p * 8 + kkl) * 64 + lane];
#pragma unroll
            for (int mf = 0; mf < 4; ++mf)
#pragma unroll
                for (int nf = 0; nf < 6; ++nf)
                    acc[mf][nf] = __builtin_amdgcn_mfma_f32_16x16x32_bf16(a[mf], b[nf],
                                                                          acc[mf][nf], 0, 0, 0);
        }
    }

    int gq = lane >> 4, cl = lane & 15;
    // stores only (terminal) — scatter rows to CSR positions
#pragma unroll
    for (int mf = 0; mf < 4; ++mf)
#pragma unroll
        for (int nf = 0; nf < 6; ++nf) {
            int c = wave * 96 + nf * 16 + cl;
            f32x4 v = acc[mf][nf];
#pragma unroll
            for (int q = 0; q < 4; ++q) {
                int row = mf * 16 + gq * 4 + q;
                msg[(size_t)s_pos[row] * 384 + c] = (unsigned short)to_bf(v[q]);
            }
        }
}

// ---------------- k_agg: SEQUENTIAL msg scan + per-edge table folds -> h1b, agg2b ----------------

__global__ void __launch_bounds__(256) k_agg(const unsigned short* __restrict__ msg,
                                             const int* __restrict__ row_off,
                                             const int* __restrict__ etC,
                                             const int* __restrict__ nidC,
                                             const int* __restrict__ node_ids,
                                             const float* __restrict__ ha1,
                                             const float* __restrict__ ecomb,
                                             const float* __restrict__ hb1,
                                             const float* __restrict__ b1,
                                             unsigned short* __restrict__ h1b,
                                             unsigned short* __restrict__ agg2b) {
    int n = blockIdx.x * 4 + (threadIdx.x >> 6);
    int lane = threadIdx.x & 63;
    if (n >= NN) return;
    int beg = row_off[n], end = row_off[n + 1];
    float d = fmaxf((float)(end - beg), 1.f);
    int nid0 = node_ids[n];
    int c = lane * 2;
    float a0 = 0.f, a1 = 0.f, a2 = 0.f, a3 = 0.f, a4 = 0.f, a5 = 0.f;
    const unsigned* m32 = (const unsigned*)msg;
    for (int i = beg; i < end; ++i) {
        int et = etC[i], nid = nidC[i];
        size_t base = (size_t)i * 192;
        unsigned u0 = m32[base + lane];
        unsigned u1 = m32[base + 64 + lane];
        unsigned u2 = m32[base + 128 + lane];
        const float2 ec0 = *(const float2*)(ecomb + (size_t)et * 384 + c);
        const float2 ec1 = *(const float2*)(ecomb + (size_t)et * 384 + 128 + c);
        const float2 ec2 = *(const float2*)(ecomb + (size_t)et * 384 + 256 + c);
        const float2 hv = *(const float2*)(ha1 + (size_t)nid * 128 + c);
        a0 += bf_to_f((unsigned short)(u0 & 0xffff)) + hv.x - ec0.x;
        a1 += bf_to_f((unsigned short)(u0 >> 16)) + hv.y - ec0.y;
        a2 += bf_to_f((unsigned short)(u1 & 0xffff)) - ec1.x;
        a3 += bf_to_f((unsigned short)(u1 >> 16)) - ec1.y;
        a4 += bf_to_f((unsigned short)(u2 & 0xffff)) - ec2.x;
        a5 += bf_to_f((unsigned short)(u2 >> 16)) - ec2.y;
    }
    const float2 hb = *(const float2*)(hb1 + (size_t)nid0 * 128 + c);
    const float2 bb = *(const float2*)(b1 + c);
    float hx = fmaxf(a0 / d + hb.x + bb.x, 0.f);
    float hy = fmaxf(a1 / d + hb.y + bb.y, 0.f);
    unsigned hp = ((unsigned)(unsigned short)to_bf(hx)) |
                  (((unsigned)(unsigned short)to_bf(hy)) << 16);
    ((unsigned*)h1b)[(size_t)n * 64 + lane] = hp;
    unsigned g0 = ((unsigned)(unsigned short)to_bf(a2)) |
                  (((unsigned)(unsigned short)to_bf(a3)) << 16);
    unsigned g1 = ((unsigned)(unsigned short)to_bf(a4)) |
                  (((unsigned)(unsigned short)to_bf(a5)) << 16);
    ((unsigned*)agg2b)[(size_t)n * 128 + lane] = g0;
    ((unsigned*)agg2b)[(size_t)n * 128 + 64 + lane] = g1;
}

// ---------------- k_s1: s1b[n] = bf16(sum over incoming edges of h1[src]) ----------------

__global__ void __launch_bounds__(256) k_s1(const unsigned short* __restrict__ h1b,
                                            const int* __restrict__ row_off,
                                            const int* __restrict__ esrcC,
                                            unsigned short* __restrict__ s1b) {
    int n = blockIdx.x * 4 + (threadIdx.x >> 6);
    int lane = threadIdx.x & 63;
    if (n >= NN) return;
    int beg = row_off[n], end = row_off[n + 1];
    float ax = 0.f, ay = 0.f;
    const unsigned* h32 = (const unsigned*)h1b;
    for (int i = beg; i < end; ++i) {
        int src = esrcC[i];
        unsigned u = h32[(size_t)src * 64 + lane];
        ax += bf_to_f((unsigned short)(u & 0xffff));
        ay += bf_to_f((unsigned short)(u >> 16));
    }
    unsigned p = ((unsigned)(unsigned short)to_bf(ax)) |
                 (((unsigned)(unsigned short)to_bf(ay)) << 16);
    ((unsigned*)s1b)[(size_t)n * 64 + lane] = p;
}

// ---------------- h2 dual GEMM + fused per-graph max -> gn ----------------

__global__ void __launch_bounds__(256) k_h2(const unsigned short* __restrict__ s1b,
                                            const unsigned short* __restrict__ h1b,
                                            const unsigned short* __restrict__ agg2b,
                                            const int* __restrict__ cnt,
                                            const int* __restrict__ n2g,
                                            const bf16x8* __restrict__ wn2f,
                                            const bf16x8* __restrict__ wl2f,
                                            const float* __restrict__ b2,
                                            float* __restrict__ gn) {
    __shared__ bf16x8 sS[1024], sH[1024];  // 16KB each
    __shared__ int s_g[64];
    int tid = threadIdx.x, n0 = blockIdx.x * 64;
    int wave = tid >> 6, lane = tid & 63;
    if (tid < 64) {
        int m = n0 + tid;
        if (m >= NN) m = NN - 1;
        s_g[tid] = n2g[m];
    }
    {
        int gsv = (tid >> 4) & 3, rsv = tid & 15;
        int row = ((tid >> 6) & 3) * 16 + rsv;
        int m = n0 + row;
        if (m >= NN) m = NN - 1;
#pragma unroll
        for (int kk = 0; kk < 4; ++kk) {
            int cb = kk * 32 + gsv * 8;
            sS[kk * 256 + tid] = *(const bf16x8*)(s1b + (size_t)m * 128 + cb);
            sH[kk * 256 + tid] = *(const bf16x8*)(h1b + (size_t)m * 128 + cb);
        }
    }
    __syncthreads();
    f32x4 aa[4][4], ab[4][4];
#pragma unroll
    for (int mf = 0; mf < 4; ++mf)
#pragma unroll
        for (int nf = 0; nf < 4; ++nf) { aa[mf][nf] = (f32x4)0.f; ab[mf][nf] = (f32x4)0.f; }
#pragma unroll
    for (int kk = 0; kk < 4; ++kk) {
        bf16x8 a1[4], a2[4], bv1[4], bv2[4];
#pragma unroll
        for (int mf = 0; mf < 4; ++mf) {
            a1[mf] = sS[kk * 256 + mf * 64 + lane];
            a2[mf] = sH[kk * 256 + mf * 64 + lane];
        }
#pragma unroll
        for (int nf = 0; nf < 4; ++nf) {
            bv1[nf] = wn2f[(size_t)((wave * 4 + nf) * 4 + kk) * 64 + lane];
            bv2[nf] = wl2f[(size_t)((wave * 4 + nf) * 4 + kk) * 64 + lane];
        }
#pragma unroll
        for (int mf = 0; mf < 4; ++mf)
#pragma unroll
            for (int nf = 0; nf < 4; ++nf) {
                aa[mf][nf] = __builtin_amdgcn_mfma_f32_16x16x32_bf16(a1[mf], bv1[nf],
                                                                     aa[mf][nf], 0, 0, 0);
                ab[mf][nf] = __builtin_amdgcn_mfma_f32_16x16x32_bf16(a2[mf], bv2[nf],
                                                                     ab[mf][nf], 0, 0, 0);
            }
    }
    int gq = lane >> 4, cl = lane & 15;
    float dinv[4][4];
#pragma unroll
    for (int mf = 0; mf < 4; ++mf)
#pragma unroll
        for (int q = 0; q < 4; ++q) {
            int m = n0 + mf * 16 + gq * 4 + q;
            if (m >= NN) m = NN - 1;
            dinv[mf][q] = 1.f / fmaxf((float)cnt[m], 1.f);
        }
    float b2v[4];
#pragma unroll
    for (int nf = 0; nf < 4; ++nf) b2v[nf] = b2[wave * 64 + nf * 16 + cl];
#pragma unroll
    for (int mf = 0; mf < 4; ++mf)
#pragma unroll
        for (int nf = 0; nf < 4; ++nf) {
            int c = wave * 64 + nf * 16 + cl;
#pragma unroll
            for (int q = 0; q < 4; ++q) {
                int m = n0 + mf * 16 + gq * 4 + q;
                if (m >= NN) m = NN - 1;
                float araw = bf_to_f(agg2b[(size_t)m * 256 + c]);
                aa[mf][nf][q] = fmaxf((araw + aa[mf][nf][q]) * dinv[mf][q]
                                      + ab[mf][nf][q] + b2v[nf], 0.f);
            }
        }
    // -------- fused per-graph max --------
    int g0 = s_g[0], g63 = s_g[63];
    if (g0 == g63) {
#pragma unroll
        for (int nf = 0; nf < 4; ++nf) {
            float mx = 0.f;
#pragma unroll
            for (int mf = 0; mf < 4; ++mf)
#pragma unroll
                for (int q = 0; q < 4; ++q) mx = fmaxf(mx, aa[mf][nf][q]);
            mx = fmaxf(mx, __shfl_xor(mx, 16));
            mx = fmaxf(mx, __shfl_xor(mx, 32));
            if (gq == 0) {
                int c = wave * 64 + nf * 16 + cl;
                atomicMax((int*)&gn[(size_t)g0 * 256 + c], __float_as_int(mx));
            }
        }
    } else {
#pragma unroll
        for (int mf = 0; mf < 4; ++mf)
#pragma unroll
            for (int q = 0; q < 4; ++q) {
                int row = mf * 16 + gq * 4 + q;
                int m = n0 + row;
                if (m >= NN) continue;
                int gg = s_g[row];
#pragma unroll
                for (int nf = 0; nf < 4; ++nf) {
                    int c = wave * 64 + nf * 16 + cl;
                    atomicMax((int*)&gn[(size_t)gg * 256 + c],
                              __float_as_int(aa[mf][nf][q]));
                }
            }
    }
}

// ---------------- per-graph edge max + output ----------------

__device__ __forceinline__ int lower_bound_i(const int* __restrict__ a, int n, int v) {
    int lo = 0, hi = n;
    while (lo < hi) {
        int m = (lo + hi) >> 1;
        if (a[m] < v) lo = m + 1; else hi = m;
    }
    return lo;
}

__global__ void k_gmax_edges(const float* __restrict__ er2, const int* __restrict__ e2g,
                             const int* __restrict__ etype, float* __restrict__ ge) {
    int g = blockIdx.x, q = blockIdx.y, j = threadIdx.x;
    int lo = lower_bound_i(e2g, NE, g);
    int hi = lower_bound_i(e2g, NE, g + 1);
    float mx = 0.f;
    for (int e = lo + q; e < hi; e += 16) mx = fmaxf(mx, er2[etype[e] * 256 + j]);
    atomicMax((int*)&ge[g * 256 + j], __float_as_int(mx));
}

__global__ void k_out(const float* __restrict__ gn, const float* __restrict__ ge,
                      const int* __restrict__ time_idx, const int* __restrict__ lens,
                      float* __restrict__ out) {
    int idx = blockIdx.x * 256 + threadIdx.x;
    const int NOUT = BNUM * SEQL * 512;
    if (idx < NOUT) {
        int j = idx & 511;
        int bt = idx >> 9;
        int b = bt / SEQL, t = bt - b * SEQL;
        float v = 0.f;
        if (t < lens[b]) {
            int g = time_idx[bt];
            v = (j < 256) ? gn[g * 256 + j] : ge[g * 256 + (j - 256)];
        }
        out[idx] = v;
    } else if (idx < NOUT + BNUM) {
        int b = idx - NOUT;
        out[idx] = (float)lens[b];
    }
}

// ---------------- launch ----------------

extern "C" void kernel_launch(void* const* d_in, const int* in_sizes, int n_in,
                              void* d_out, int out_size, void* d_ws, size_t ws_size,
                              hipStream_t stream) {
    const int*   node_ids  = (const int*)d_in[0];
    const int*   edge_src  = (const int*)d_in[1];
    const int*   edge_dst  = (const int*)d_in[2];
    const int*   edge_type = (const int*)d_in[3];
    const int*   node2g    = (const int*)d_in[4];
    const int*   edge2g    = (const int*)d_in[5];
    const float* text_emb  = (const float*)d_in[6];
    const int*   time_idx  = (const int*)d_in[7];
    const int*   lens      = (const int*)d_in[8];
    const float* ent_emb   = (const float*)d_in[9];
    const float* ent_mem   = (const float*)d_in[10];
    const float* rel_emb   = (const float*)d_in[11];
    const float* rel_mem   = (const float*)d_in[12];
    const float* w_node_W  = (const float*)d_in[13];
    const float* w_node_b  = (const float*)d_in[14];
    const float* w_rel_W   = (const float*)d_in[15];
    const float* w_rel_b   = (const float*)d_in[16];
    const float* Wn1 = (const float*)d_in[17];
    const float* Wl1 = (const float*)d_in[18];
    const float* Wt1 = (const float*)d_in[19];
    const float* Wr1 = (const float*)d_in[20];
    const float* b1  = (const float*)d_in[21];
    const float* Wn2 = (const float*)d_in[22];
    const float* Wl2 = (const float*)d_in[23];
    const float* Wt2 = (const float*)d_in[24];
    const float* Wr2 = (const float*)d_in[25];
    const float* b2  = (const float*)d_in[26];

    float* ws = (float*)d_ws;
    size_t off = 0;
    float* rel_feat = ws + off; off += (size_t)NREL * 256;
    float* er1      = ws + off; off += (size_t)NREL * 128;
    float* er2      = ws + off; off += (size_t)NREL * 256;
    float* ecomb    = ws + off; off += (size_t)NREL * 384;
    float* ha1      = ws + off; off += (size_t)NENT * 128;
    float* hb1      = ws + off; off += (size_t)NENT * 128;
    float* cw       = ws + off; off += (size_t)768 * 256;
    float* bc       = ws + off; off += 256;
    bf16x8* wtf  = (bf16x8*)(ws + off); off += (size_t)24 * 16 * 64 * 4;  // 384KB
    bf16x8* cwf  = (bf16x8*)(ws + off); off += (size_t)16 * 24 * 64 * 4;  // 384KB
    bf16x8* wn2f = (bf16x8*)(ws + off); off += (size_t)16 * 4 * 64 * 4;   // 64KB
    bf16x8* wl2f = (bf16x8*)(ws + off); off += (size_t)16 * 4 * 64 * 4;   // 64KB
    // ---- zero region: cnt | gn | ge ----
    int*   cnt = (int*)(ws + off);
    size_t zoff = off;          off += 100096;
    float* gn  = ws + off;      off += (size_t)GNUM * 256;
    float* ge  = ws + off;      off += (size_t)GNUM * 256;
    size_t zbytes = (off - zoff) * sizeof(float);
    // ---- CSR arrays ----
    int* row_off = (int*)(ws + off); off += 100352;
    int* cur     = (int*)(ws + off); off += 100096;
    int* bsum    = (int*)(ws + off); off += 512;
    int* pinv    = (int*)(ws + off); off += (size_t)NE;
    int* esrcC   = (int*)(ws + off); off += (size_t)NE;
    int* etC     = (int*)(ws + off); off += (size_t)NE;
    int* nidC    = (int*)(ws + off); off += (size_t)NE;
    // ---- big buffers ----
    unsigned short* msg = (unsigned short*)(ws + off);
    unsigned short* s1b = (unsigned short*)(ws + off);  // aliases msg (dead before k_s1)
    off += (size_t)NE * 384 / 2;
    unsigned short* h1b   = (unsigned short*)(ws + off); off += (size_t)NN * 64;
    unsigned short* agg2b = (unsigned short*)(ws + off); off += (size_t)NN * 128;

    hipMemsetAsync((void*)cnt, 0, zbytes, stream);

    // CSR
    k_cnt<<<(NE + 255) / 256, 256, 0, stream>>>(edge_dst, cnt);
    k_scan_blk<<<391, 256, 0, stream>>>(cnt, row_off, bsum);
    k_scan_top<<<1, 512, 0, stream>>>(bsum);
    k_scan_add<<<391, 256, 0, stream>>>(row_off, bsum, cur);
    k_fill<<<(NE + 255) / 256, 256, 0, stream>>>(edge_dst, edge_src, edge_type, node_ids,
                                                 cur, pinv, esrcC, etC, nidC);

    // relation-side (tiny)
    k_rel_feat<<<NREL, 256, 0, stream>>>(rel_emb, rel_mem, w_rel_W, w_rel_b, rel_feat);
    k_rel_l1<<<NREL, 256, 0, stream>>>(rel_feat, Wn1, Wr1, ecomb, er1);
    k_rel_l2<<<NREL, 256, 0, stream>>>(er1, Wr2, Wn2, er2, ecomb);

    // combined node weights + packing
    k_cw<<<768, 256, 0, stream>>>(w_node_W, Wn1, Wl1, cw);
    k_cb<<<1, 256, 0, stream>>>(w_node_b, Wn1, Wl1, bc);
    k_pack<<<8 * 16, 64, 0, stream>>>(Wt1, wtf, 512, 128);
    k_pack<<<16 * 16, 64, 0, stream>>>(Wt2, wtf + (size_t)8 * 16 * 64, 512, 256);
    k_pack<<<16 * 24, 64, 0, stream>>>(cw, cwf, 768, 256);
    k_pack<<<16 * 4, 64, 0, stream>>>(Wn2, wn2f, 128, 256);
    k_pack<<<16 * 4, 64, 0, stream>>>(Wl2, wl2f, 128, 256);

    // entity GEMM -> ha1, hb1
    k_ent<<<(NENT + 63) / 64, 256, 0, stream>>>(ent_emb, ent_mem, cwf, bc, ha1, hb1);

    // edge GEMM: streaming read, CSR-scatter write -> msg
    k_edge<<<NE / 64, 256, 0, stream>>>(text_emb, pinv, wtf, msg);

    // sequential msg scan + fold -> h1b, agg2b (bf16)
    k_agg<<<NN / 4, 256, 0, stream>>>(msg, row_off, etC, nidC, node_ids,
                                      ha1, ecomb, hb1, b1, h1b, agg2b);
    // gather s1 (bf16; aliases msg region — msg dead now)
    k_s1<<<NN / 4, 256, 0, stream>>>(h1b, row_off, esrcC, s1b);
    // dual GEMM + fused per-graph node max -> gn
    k_h2<<<(NN + 63) / 64, 256, 0, stream>>>(s1b, h1b, agg2b, cnt, node2g,
                                             wn2f, wl2f, b2, gn);

    k_gmax_edges<<<dim3(GNUM, 16), 256, 0, stream>>>(er2, edge2g, edge_type, ge);
    k_out<<<(BNUM * SEQL * 512 + BNUM + 255) / 256, 256, 0, stream>>>(gn, ge, time_idx, lens,
                                                                      (float*)d_out);
}